// Round 14
// baseline (131.070 us; speedup 1.0000x reference)
//
#include <hip/hip_runtime.h>

typedef __attribute__((ext_vector_type(8))) short bf16x8;
typedef __attribute__((ext_vector_type(4))) float f32x4;
typedef __attribute__((ext_vector_type(2))) float f32x2;
typedef __attribute__((ext_vector_type(2))) unsigned int u32x2;

// x_t: padded NHWC bf16 [32 img][58 prow][58 pcol][64 c]  = 13,778,944 B
#define XT_BYTES ((size_t)32 * 3364 * 64 * 2)
#define W2_OFF   XT_BYTES
// weff2: [512 n][16 tap][64 c] bf16 = 1 MB
#define NEED_WS2 (XT_BYTES + (size_t)512 * 1024 * 2)

static __device__ __forceinline__ unsigned short f2bf(float v) {
    unsigned int u = __builtin_bit_cast(unsigned int, v);
    u += 0x7fffu + ((u >> 16) & 1u);
    return (unsigned short)(u >> 16);
}

// ---------------------------------------------------------------------------
// prep_xt: bid<896 -> NHWC transpose+pad (block = (img, xrow-pair));
//          bid>=896 -> Hadamard-folded weights weff2[n][tap][c].
// ---------------------------------------------------------------------------
__global__ __launch_bounds__(256) void prep_xt(const float* __restrict__ x,
                                               const float* __restrict__ w,
                                               unsigned char* __restrict__ ws)
{
    const int bid = blockIdx.x;
    const int tid = threadIdx.x;
    if (bid < 896) {
        __shared__ float lds[64][117];   // [c][r*58 + pcol], odd pitch
        const int img = bid / 28, rp = bid - img * 28;

        float* lf = &lds[0][0];
        for (int i = tid; i < 64 * 117; i += 256) lf[i] = 0.f;
        __syncthreads();

        // load 2 x-rows (112 f32, contiguous) per channel; dense f32x4
        {
            const int c = tid >> 2, j0 = tid & 3;
            const float* src = x + ((size_t)(img * 64 + c) * 3136 + rp * 112);
            #pragma unroll
            for (int i = 0; i < 7; ++i) {
                f32x4 v = *(const f32x4*)(src + (j0 + 4 * i) * 4);
                #pragma unroll
                for (int d = 0; d < 4; ++d) {
                    int e = (j0 + 4 * i) * 4 + d;
                    int r = e / 56, cl = e - r * 56;
                    lds[c][r * 58 + cl + 1] = v[d];
                }
            }
        }
        __syncthreads();

        // emit: prow = 2rp+1+r, [pcol][c] contiguous; borders are LDS zeros
        unsigned short* xt = (unsigned short*)ws;
        const int c4 = tid & 15, colb = tid >> 4;
        #pragma unroll
        for (int r = 0; r < 2; ++r) {
            const size_t pbase = ((size_t)img * 3364 + (size_t)(2 * rp + 1 + r) * 58) * 64;
            #pragma unroll
            for (int it = 0; it < 4; ++it) {
                int col = colb + it * 16;
                if (col < 58) {
                    unsigned int lo = (unsigned)f2bf(lds[c4 * 4 + 0][r * 58 + col])
                                    | ((unsigned)f2bf(lds[c4 * 4 + 1][r * 58 + col]) << 16);
                    unsigned int hi = (unsigned)f2bf(lds[c4 * 4 + 2][r * 58 + col])
                                    | ((unsigned)f2bf(lds[c4 * 4 + 3][r * 58 + col]) << 16);
                    u32x2 st = {lo, hi};
                    *(u32x2*)(xt + pbase + (size_t)col * 64 + c4 * 4) = st;
                }
            }
        }
        // border planes prow 0 / 57
        if (rp == 0 || rp == 27) {
            const int prow = (rp == 0) ? 0 : 57;
            unsigned int* p32 = (unsigned int*)((unsigned short*)ws
                              + ((size_t)img * 3364 + (size_t)prow * 58) * 64);
            for (int i = tid; i < 58 * 32; i += 256) p32[i] = 0u;
        }
        return;
    }

    int idx = (bid - 896) * 256 + tid;            // (o,c)
    if (idx >= 128 * 64) return;
    int o = idx >> 6, c = idx & 63;
    const bool v2 = (o >= 64);
    const float Hm[4][4]  = {{1,1,1,1},{1,-1,1,-1},{1,1,-1,-1},{1,-1,-1,1}};
    const float H2m[4][4] = {{1,-1,1,-1},{1,1,1,1},{1,1,-1,-1},{1,-1,-1,1}};
    float wv[4][4];
    #pragma unroll
    for (int i = 0; i < 4; ++i)
        #pragma unroll
        for (int j = 0; j < 4; ++j)
            wv[i][j] = w[((o * 64 + c) * 4 + i) * 4 + j];
    float FA[4][4], FB[4][4], G[2][4];
    #pragma unroll
    for (int a = 0; a < 4; ++a)
        #pragma unroll
        for (int i = 0; i < 4; ++i) {
            FA[a][i] = v2 ? H2m[a][i] : Hm[i][a];
            FB[a][i] = v2 ? H2m[a][i] : Hm[a][i];
        }
    #pragma unroll
    for (int p = 0; p < 2; ++p)
        #pragma unroll
        for (int i = 0; i < 4; ++i)
            G[p][i] = 0.25f * (v2 ? H2m[p + 1][i] : Hm[p + 1][i]);
    unsigned short* weff = (unsigned short*)(ws + W2_OFF);
    #pragma unroll
    for (int P = 0; P < 2; ++P)
    #pragma unroll
    for (int Q = 0; Q < 2; ++Q) {
        int nrow = o * 4 + P * 2 + Q;
        #pragma unroll
        for (int b = 0; b < 4; ++b)
        #pragma unroll
        for (int a = 0; a < 4; ++a) {
            float s = 0.f;
            #pragma unroll
            for (int i = 0; i < 4; ++i) {
                float sj = 0.f;
                #pragma unroll
                for (int j = 0; j < 4; ++j)
                    sj += FB[b][j] * G[Q][j] * wv[i][j];
                s += G[P][i] * FA[a][i] * sj;
            }
            // k = tap*64 + c, tap = b*4 + a
            weff[(size_t)nrow * 1024 + (b * 4 + a) * 64 + c] = f2bf(s);
        }
    }
}

// ---------------------------------------------------------------------------
// conv_gemm4: barrier-free direct-fragment GEMM on padded NHWC x_t.
// M=25088 (196x128), N=512 (4x128), K=1024 (16 taps x 64 c).
// Block 256 thr = 4 waves (2m x 2n); wave 64x64 (fm4 x fn4), 32 MFMA/tap.
// A-frag (fm,ks): 16 t-rows x one full 64B line  -> dense direct load.
// B-frag: n-major weff2 row, 16B/lane            -> dense direct load.
// 2-deep named fragment sets F0/F1: loads(k+1) fly under MFMA(k); no LDS,
// no barriers in the K-loop; waves fully independent (TLP hides latency).
// ---------------------------------------------------------------------------
__global__ __launch_bounds__(256, 2) void conv_gemm4(
    const unsigned char* __restrict__ xt,
    const unsigned char* __restrict__ wf,
    const float* __restrict__ bias,
    float* __restrict__ out)
{
    __shared__ float esc_s[4 * 1088];
    __shared__ int s_obase[128];

    const int tid  = threadIdx.x;
    const int lane = tid & 63;
    const int l15  = lane & 15;
    const int g    = lane >> 4;
    const int wv   = tid >> 6;                 // 0..3
    const int wm   = wv >> 1, wn = wv & 1;     // 2m x 2n
    const int bid  = blockIdx.x;
    const int wid  = (bid & 7) * 98 + (bid >> 3);   // bijective XCD swizzle
    const int tg   = wid >> 2, ngrp = wid & 3;
    const int t0   = tg << 7;
    const int n0g  = ngrp << 7;

    if (tid < 128) {
        int t = t0 + tid;
        int nimg = t / 784, rem = t - nimg * 784;
        int h = rem / 28, w2 = rem - h * 28;
        s_obase[tid] = nimg * 401408 + (2 * h) * 56 + 2 * w2;
    }
    __syncthreads();

    // A bases: lane's t per fm -> (img, 2h, 2w) in padded NHWC, + c-chunk g
    unsigned int pA[4];
    #pragma unroll
    for (int fm = 0; fm < 4; ++fm) {
        int t = t0 + wm * 64 + fm * 16 + l15;
        int img = t / 784, rem = t - img * 784;
        int h = rem / 28, w2 = rem - h * 28;
        pA[fm] = (unsigned)((img * 3364 + (2 * h) * 58 + 2 * w2) * 128 + g * 16);
    }
    // B bases: n-major rows of 2048 B
    unsigned int pB[4];
    #pragma unroll
    for (int fn = 0; fn < 4; ++fn)
        pB[fn] = (unsigned)((n0g + wn * 64 + fn * 16 + l15) * 2048 + g * 16);

    f32x4 acc[4][4];
    #pragma unroll
    for (int i = 0; i < 4; ++i)
        #pragma unroll
        for (int j = 0; j < 4; ++j)
            acc[i][j] = (f32x4){0.f, 0.f, 0.f, 0.f};

    struct Frags { bf16x8 a[4][2]; bf16x8 b[4][2]; };

    auto LOADF = [&](int tap, Frags& F) {
        const int b = tap >> 2, a = tap & 3;
        const unsigned int ao = (unsigned)((b * 58 + a) * 128);
        const unsigned int bo = (unsigned)(tap * 128);
        #pragma unroll
        for (int fm = 0; fm < 4; ++fm)
            #pragma unroll
            for (int ks = 0; ks < 2; ++ks)
                F.a[fm][ks] = *(const bf16x8*)(xt + (pA[fm] + ao + ks * 64));
        #pragma unroll
        for (int fn = 0; fn < 4; ++fn)
            #pragma unroll
            for (int ks = 0; ks < 2; ++ks)
                F.b[fn][ks] = *(const bf16x8*)(wf + (pB[fn] + bo + ks * 64));
    };
    auto MFMAF = [&](Frags& F) {
        __builtin_amdgcn_s_setprio(1);
        #pragma unroll
        for (int ks = 0; ks < 2; ++ks)
            #pragma unroll
            for (int fm = 0; fm < 4; ++fm)
                #pragma unroll
                for (int fn = 0; fn < 4; ++fn)
                    acc[fm][fn] = __builtin_amdgcn_mfma_f32_16x16x32_bf16(
                        F.a[fm][ks], F.b[fn][ks], acc[fm][fn], 0, 0, 0);
        __builtin_amdgcn_s_setprio(0);
    };

    Frags F0, F1;
    LOADF(0, F0);
    #pragma unroll
    for (int k = 0; k < 14; k += 2) {
        LOADF(k + 1, F1);      // in flight under MFMA(F0)
        MFMAF(F0);
        LOADF(k + 2, F0);      // in flight under MFMA(F1)
        MFMAF(F1);
    }
    LOADF(15, F1);
    MFMAF(F0);
    MFMAF(F1);

    // epilogue: per-wave LDS transpose -> contiguous f32x2 stores (verified)
    float bfn[4];
    #pragma unroll
    for (int fn = 0; fn < 4; ++fn)
        bfn[fn] = bias[(n0g + wn * 64 + fn * 16 + l15) >> 2];
    const int ob = s_obase[wm * 64 + lane];
    float* esc = esc_s + wv * 1088;

    #pragma unroll
    for (int fn = 0; fn < 4; ++fn) {
        #pragma unroll
        for (int fm = 0; fm < 4; ++fm)
            #pragma unroll
            for (int r = 0; r < 4; ++r)
                esc[(fm * 16 + g * 4 + r) * 17 + l15] = acc[fm][fn][r] + bfn[fn];
        asm volatile("s_waitcnt lgkmcnt(0)" ::: "memory");
        __builtin_amdgcn_sched_barrier(0);
        const int ncb = n0g + wn * 64 + fn * 16;
        #pragma unroll
        for (int jp = 0; jp < 8; ++jp) {
            float v0 = esc[lane * 17 + 2 * jp];
            float v1 = esc[lane * 17 + 2 * jp + 1];
            int n = ncb + 2 * jp;
            int o = n >> 2, P = (n >> 1) & 1;
            f32x2 st = {v0, v1};
            *(f32x2*)(out + ob + o * 3136 + P * 56) = st;
        }
        asm volatile("s_waitcnt lgkmcnt(0)" ::: "memory");
        __builtin_amdgcn_sched_barrier(0);
    }
}

extern "C" void kernel_launch(void* const* d_in, const int* in_sizes, int n_in,
                              void* d_out, int out_size, void* d_ws, size_t ws_size,
                              hipStream_t stream)
{
    const float* x = (const float*)d_in[0];
    const float* w = (const float*)d_in[1];
    const float* b = (const float*)d_in[2];
    float* out = (float*)d_out;
    unsigned char* ws = (unsigned char*)d_ws;

    hipLaunchKernelGGL(prep_xt, dim3(896 + 32), dim3(256), 0, stream, x, w, ws);
    hipLaunchKernelGGL(conv_gemm4, dim3(784), dim3(256), 0, stream,
                       ws, ws + W2_OFF, b, out);
}

// Round 15
// 52.775 us; speedup vs baseline: 2.4836x; 2.4836x over previous
//
#include <hip/hip_runtime.h>

typedef __attribute__((ext_vector_type(8))) short bf16x8;
typedef __attribute__((ext_vector_type(4))) float f32x4;
typedef __attribute__((ext_vector_type(2))) float f32x2;
typedef __attribute__((ext_vector_type(2))) unsigned int u32x2;

// x_t: padded NHWC bf16 [32 img][58 prow][58 pcol][64 c]  = 13,778,944 B
#define XT_BYTES ((size_t)32 * 3364 * 64 * 2)
#define W2_OFF   XT_BYTES
// weff2: [512 n][16 tap][64 c] bf16 = 1 MB

static __device__ __forceinline__ unsigned short f2bf(float v) {
    unsigned int u = __builtin_bit_cast(unsigned int, v);
    u += 0x7fffu + ((u >> 16) & 1u);
    return (unsigned short)(u >> 16);
}
static __device__ __forceinline__ void gload_lds16(const void* g, void* l) {
    __builtin_amdgcn_global_load_lds(
        (const __attribute__((address_space(1))) void*)g,
        (__attribute__((address_space(3))) void*)l, 16, 0, 0);
}

// ---------------------------------------------------------------------------
// prep_xt (verified r14): bid<896 -> NHWC transpose+pad (block=(img,xrow-pair))
//                         bid>=896 -> Hadamard-folded weights weff2[n][tap][c]
// ---------------------------------------------------------------------------
__global__ __launch_bounds__(256) void prep_xt(const float* __restrict__ x,
                                               const float* __restrict__ w,
                                               unsigned char* __restrict__ ws)
{
    const int bid = blockIdx.x;
    const int tid = threadIdx.x;
    if (bid < 896) {
        __shared__ float lds[64][117];   // [c][r*58 + pcol], odd pitch
        const int img = bid / 28, rp = bid - img * 28;

        float* lf = &lds[0][0];
        for (int i = tid; i < 64 * 117; i += 256) lf[i] = 0.f;
        __syncthreads();

        {
            const int c = tid >> 2, j0 = tid & 3;
            const float* src = x + ((size_t)(img * 64 + c) * 3136 + rp * 112);
            #pragma unroll
            for (int i = 0; i < 7; ++i) {
                f32x4 v = *(const f32x4*)(src + (j0 + 4 * i) * 4);
                #pragma unroll
                for (int d = 0; d < 4; ++d) {
                    int e = (j0 + 4 * i) * 4 + d;
                    int r = e / 56, cl = e - r * 56;
                    lds[c][r * 58 + cl + 1] = v[d];
                }
            }
        }
        __syncthreads();

        unsigned short* xt = (unsigned short*)ws;
        const int c4 = tid & 15, colb = tid >> 4;
        #pragma unroll
        for (int r = 0; r < 2; ++r) {
            const size_t pbase = ((size_t)img * 3364 + (size_t)(2 * rp + 1 + r) * 58) * 64;
            #pragma unroll
            for (int it = 0; it < 4; ++it) {
                int col = colb + it * 16;
                if (col < 58) {
                    unsigned int lo = (unsigned)f2bf(lds[c4 * 4 + 0][r * 58 + col])
                                    | ((unsigned)f2bf(lds[c4 * 4 + 1][r * 58 + col]) << 16);
                    unsigned int hi = (unsigned)f2bf(lds[c4 * 4 + 2][r * 58 + col])
                                    | ((unsigned)f2bf(lds[c4 * 4 + 3][r * 58 + col]) << 16);
                    u32x2 st = {lo, hi};
                    *(u32x2*)(xt + pbase + (size_t)col * 64 + c4 * 4) = st;
                }
            }
        }
        if (rp == 0 || rp == 27) {
            const int prow = (rp == 0) ? 0 : 57;
            unsigned int* p32 = (unsigned int*)((unsigned short*)ws
                              + ((size_t)img * 3364 + (size_t)prow * 58) * 64);
            for (int i = tid; i < 58 * 32; i += 256) p32[i] = 0u;
        }
        return;
    }

    int idx = (bid - 896) * 256 + tid;            // (o,c)
    if (idx >= 128 * 64) return;
    int o = idx >> 6, c = idx & 63;
    const bool v2 = (o >= 64);
    const float Hm[4][4]  = {{1,1,1,1},{1,-1,1,-1},{1,1,-1,-1},{1,-1,-1,1}};
    const float H2m[4][4] = {{1,-1,1,-1},{1,1,1,1},{1,1,-1,-1},{1,-1,-1,1}};
    float wv[4][4];
    #pragma unroll
    for (int i = 0; i < 4; ++i)
        #pragma unroll
        for (int j = 0; j < 4; ++j)
            wv[i][j] = w[((o * 64 + c) * 4 + i) * 4 + j];
    float FA[4][4], FB[4][4], G[2][4];
    #pragma unroll
    for (int a = 0; a < 4; ++a)
        #pragma unroll
        for (int i = 0; i < 4; ++i) {
            FA[a][i] = v2 ? H2m[a][i] : Hm[i][a];
            FB[a][i] = v2 ? H2m[a][i] : Hm[a][i];
        }
    #pragma unroll
    for (int p = 0; p < 2; ++p)
        #pragma unroll
        for (int i = 0; i < 4; ++i)
            G[p][i] = 0.25f * (v2 ? H2m[p + 1][i] : Hm[p + 1][i]);
    unsigned short* weff = (unsigned short*)(ws + W2_OFF);
    #pragma unroll
    for (int P = 0; P < 2; ++P)
    #pragma unroll
    for (int Q = 0; Q < 2; ++Q) {
        int nrow = o * 4 + P * 2 + Q;
        #pragma unroll
        for (int b = 0; b < 4; ++b)
        #pragma unroll
        for (int a = 0; a < 4; ++a) {
            float s = 0.f;
            #pragma unroll
            for (int i = 0; i < 4; ++i) {
                float sj = 0.f;
                #pragma unroll
                for (int j = 0; j < 4; ++j)
                    sj += FB[b][j] * G[Q][j] * wv[i][j];
                s += G[P][i] * FA[a][i] * sj;
            }
            weff[(size_t)nrow * 1024 + (b * 4 + a) * 64 + c] = f2bf(s);
        }
    }
}

// ---------------------------------------------------------------------------
// conv_gemm5: r12-proven staged GEMM, de-duplicated wave decomposition.
// M=25088 (196x128), N=512 (4x128), K=1024 (16 taps x 64 c).
// 256 thr = 4 waves (2m x 2n); wave = 64x64, 32 MFMA(16x16x32)/step.
// A from padded NHWC xt (per-tile base table + per-tap imm offset);
// B from weff2[n][tap][c]. Both staged via global_load_lds w=16 from
// pre-swizzled per-lane sources (rule #21), double-buffered, counted
// vmcnt(8) — never drained. LDS/step: 64KB read + 32KB write (was 128KB).
// ---------------------------------------------------------------------------
__global__ __launch_bounds__(256, 2) void conv_gemm5(
    const unsigned char* __restrict__ xt,
    const unsigned char* __restrict__ wf,
    const float* __restrict__ bias,
    float* __restrict__ out)
{
    __shared__ __align__(16) unsigned char smem[65536]; // A0,A1,B0,B1 16KB each
    __shared__ int s_abase[128];
    __shared__ int s_obase[128];

    const int tid  = threadIdx.x;
    const int lane = tid & 63;
    const int l15  = lane & 15;
    const int g    = lane >> 4;
    const int wv   = tid >> 6;                 // 0..3
    const int wm   = wv >> 1, wn = wv & 1;     // 2m x 2n
    const int bid  = blockIdx.x;
    const int wid  = (bid & 7) * 98 + (bid >> 3);   // bijective XCD swizzle
    const int tg   = wid >> 2, ngrp = wid & 3;
    const int t0   = tg << 7;
    const int n0g  = ngrp << 7;

    if (tid < 128) {
        int t = t0 + tid;
        int img = t / 784, rem = t - img * 784;
        int h = rem / 28, w2 = rem - h * 28;
        s_abase[tid] = (img * 3364 + (2 * h) * 58 + 2 * w2) * 128;
        s_obase[tid] = img * 401408 + (2 * h) * 56 + 2 * w2;
    }
    __syncthreads();

    // staging roles: instr j covers LDS rows wv*32+j*8 .. +7, slot = lane&7
    const int sr      = lane >> 3;             // 0..7 (row within group)
    const int slot    = lane & 7;
    const int srcslot = slot ^ sr;             // inverse-swizzled source chunk
    const unsigned char* asrc[4];
    const unsigned char* bsrc[4];
    unsigned int adst[4];
    #pragma unroll
    for (int j = 0; j < 4; ++j) {
        int row = wv * 32 + j * 8 + sr;
        asrc[j] = xt + (unsigned)(s_abase[row] + srcslot * 16);
        bsrc[j] = wf + (unsigned)((n0g + row) * 2048 + srcslot * 16);
        adst[j] = (unsigned)((wv * 32 + j * 8) * 128);   // wave-uniform
    }

    // fragment read bases (read-side swizzle, 2-way free)
    const int fswz = (l15 & 7) << 4;
    int abase[4], bbase[4];
    #pragma unroll
    for (int fm = 0; fm < 4; ++fm)
        abase[fm] = (wm * 64 + fm * 16 + l15) * 128 + g * 16;
    #pragma unroll
    for (int fn = 0; fn < 4; ++fn)
        bbase[fn] = (wn * 64 + fn * 16 + l15) * 128 + g * 16;

    f32x4 acc[4][4];
    #pragma unroll
    for (int i = 0; i < 4; ++i)
        #pragma unroll
        for (int j = 0; j < 4; ++j)
            acc[i][j] = (f32x4){0.f, 0.f, 0.f, 0.f};

    auto STAGE = [&](int k, int buf) {
        const unsigned int ao = (unsigned)(((k >> 2) * 58 + (k & 3)) * 128);
        const unsigned int bo = (unsigned)(k * 128);
        unsigned char* Ab = smem + buf * 16384;
        unsigned char* Bb = smem + 32768 + buf * 16384;
        #pragma unroll
        for (int j = 0; j < 4; ++j) {
            gload_lds16(asrc[j] + ao, Ab + adst[j]);
            gload_lds16(bsrc[j] + bo, Bb + adst[j]);
        }
    };
    auto MFMA_STEP = [&](int buf) {
        const unsigned char* Ab = smem + buf * 16384;
        const unsigned char* Bb = smem + 32768 + buf * 16384;
        __builtin_amdgcn_s_setprio(1);
        #pragma unroll
        for (int ks = 0; ks < 2; ++ks) {
            bf16x8 af[4], bg[4];
            #pragma unroll
            for (int fm = 0; fm < 4; ++fm)
                af[fm] = *(const bf16x8*)(Ab + ((abase[fm] | (ks << 6)) ^ fswz));
            #pragma unroll
            for (int fn = 0; fn < 4; ++fn)
                bg[fn] = *(const bf16x8*)(Bb + ((bbase[fn] | (ks << 6)) ^ fswz));
            #pragma unroll
            for (int fm = 0; fm < 4; ++fm)
                #pragma unroll
                for (int fn = 0; fn < 4; ++fn)
                    acc[fm][fn] = __builtin_amdgcn_mfma_f32_16x16x32_bf16(
                        af[fm], bg[fn], acc[fm][fn], 0, 0, 0);
        }
        __builtin_amdgcn_s_setprio(0);
    };

    // prologue
    STAGE(0, 0);
    asm volatile("s_waitcnt vmcnt(0)" ::: "memory");
    __builtin_amdgcn_s_barrier();
    __builtin_amdgcn_sched_barrier(0);

#define STEP(K, LAST)                                                        \
    do {                                                                     \
        if (!(LAST)) {                                                       \
            STAGE((K) + 1, ((K) + 1) & 1);                                   \
            asm volatile("s_waitcnt vmcnt(8)" ::: "memory");                 \
        } else {                                                             \
            asm volatile("s_waitcnt vmcnt(0)" ::: "memory");                 \
        }                                                                    \
        __builtin_amdgcn_s_barrier();                                        \
        __builtin_amdgcn_sched_barrier(0);                                   \
        MFMA_STEP((K) & 1);                                                  \
        __builtin_amdgcn_s_barrier();                                        \
        __builtin_amdgcn_sched_barrier(0);                                   \
    } while (0)

    STEP(0, 0);  STEP(1, 0);  STEP(2, 0);  STEP(3, 0);
    STEP(4, 0);  STEP(5, 0);  STEP(6, 0);  STEP(7, 0);
    STEP(8, 0);  STEP(9, 0);  STEP(10, 0); STEP(11, 0);
    STEP(12, 0); STEP(13, 0); STEP(14, 0); STEP(15, 1);
#undef STEP

    // epilogue (verified): per-wave LDS transpose -> contiguous f32x2 stores
    float bfn[4];
    #pragma unroll
    for (int fn = 0; fn < 4; ++fn)
        bfn[fn] = bias[(n0g + wn * 64 + fn * 16 + l15) >> 2];
    const int ob = s_obase[wm * 64 + lane];
    float* esc = (float*)smem + wv * 1088;

    #pragma unroll
    for (int fn = 0; fn < 4; ++fn) {
        #pragma unroll
        for (int fm = 0; fm < 4; ++fm)
            #pragma unroll
            for (int r = 0; r < 4; ++r)
                esc[(fm * 16 + g * 4 + r) * 17 + l15] = acc[fm][fn][r] + bfn[fn];
        asm volatile("s_waitcnt lgkmcnt(0)" ::: "memory");
        __builtin_amdgcn_sched_barrier(0);
        const int ncb = n0g + wn * 64 + fn * 16;
        #pragma unroll
        for (int jp = 0; jp < 8; ++jp) {
            float v0 = esc[lane * 17 + 2 * jp];
            float v1 = esc[lane * 17 + 2 * jp + 1];
            int n = ncb + 2 * jp;
            int o = n >> 2, P = (n >> 1) & 1;
            f32x2 st = {v0, v1};
            *(f32x2*)(out + ob + o * 3136 + P * 56) = st;
        }
        asm volatile("s_waitcnt lgkmcnt(0)" ::: "memory");
        __builtin_amdgcn_sched_barrier(0);
    }
}

extern "C" void kernel_launch(void* const* d_in, const int* in_sizes, int n_in,
                              void* d_out, int out_size, void* d_ws, size_t ws_size,
                              hipStream_t stream)
{
    const float* x = (const float*)d_in[0];
    const float* w = (const float*)d_in[1];
    const float* b = (const float*)d_in[2];
    float* out = (float*)d_out;
    unsigned char* ws = (unsigned char*)d_ws;

    hipLaunchKernelGGL(prep_xt, dim3(896 + 32), dim3(256), 0, stream, x, w, ws);
    hipLaunchKernelGGL(conv_gemm5, dim3(784), dim3(256), 0, stream,
                       ws, ws + W2_OFF, b, out);
}